// Round 24
// baseline (201.072 us; speedup 1.0000x reference)
//
#include <hip/hip_runtime.h>
#include <hip/hip_bf16.h>
#include <math.h>

#define KDIM 256
#define RATIO_T 0.9f
#define EPS_T 1e-8f
#define FNS 16

// fallback geometry (round-2 verified)
#define FBM 128
#define FBN 128
#define FBK 16
#define BM 64
#define BN 64
#define BKS 16

typedef _Float16 f16x8 __attribute__((ext_vector_type(8)));
typedef float f32x4 __attribute__((ext_vector_type(4)));
typedef unsigned short ushort_t;

// 1 / ||column i|| for TWO matrices in one launch: i<n -> A, else B.
__global__ void norms2_kernel(const float* __restrict__ A, const float* __restrict__ B,
                              float* __restrict__ invA, float* __restrict__ invB, int n) {
    int i = blockIdx.x * blockDim.x + threadIdx.x;
    if (i >= 2 * n) return;
    const float* X = (i < n) ? A : B;
    float* out = (i < n) ? invA : invB;
    int c = (i < n) ? i : i - n;
    float s = 0.f;
#pragma unroll 8
    for (int k = 0; k < KDIM; ++k) {
        float v = X[(size_t)k * n + c];
        s += v * v;
    }
    out[c] = 1.0f / sqrtf(s);
}

// fp16 split for TWO matrices in one launch (first half A, second half B).
// frag layout: 16B unit index = ((bm*8 + s)*8 + fm)*64 + g*16 + lm
__global__ void split2_kernel(const float* __restrict__ A, const float* __restrict__ B,
                              ushort_t* __restrict__ Ahh, ushort_t* __restrict__ Al6,
                              ushort_t* __restrict__ Bhh, ushort_t* __restrict__ Bl6, int n) {
    int tid = blockIdx.x * blockDim.x + threadIdx.x;   // 2*n*32 threads total
    int half = (tid >= n * 32) ? 1 : 0;
    int t2 = tid - half * n * 32;
    const float* X = half ? B : A;
    ushort_t* Xh = half ? Bhh : Ahh;
    ushort_t* Xl = half ? Bl6 : Al6;
    int lane = t2 & 63;
    int rest = t2 >> 6;
    int kg = rest & 31, iblk = rest >> 5;
    int i = iblk * 64 + lane;
    if (i >= n) return;
    float x[8];
#pragma unroll
    for (int e = 0; e < 8; ++e) x[e] = X[(size_t)(kg * 8 + e) * n + i];
    union { ushort_t us[8]; uint4 v; } ph, pl;
#pragma unroll
    for (int e = 0; e < 8; ++e) {
        _Float16 hh = (_Float16)x[e];
        float r = x[e] - (float)hh;
        _Float16 ll = (_Float16)(r * 64.0f);
        ph.us[e] = __builtin_bit_cast(ushort_t, hh);
        pl.us[e] = __builtin_bit_cast(ushort_t, ll);
    }
    int bm = i >> 7, fm = (i >> 4) & 7, lmm = i & 15;
    int sk = kg >> 2, gg = kg & 3;
    size_t off16 = ((((size_t)bm * 8 + sk) * 8 + fm) * 64) + gg * 16 + lmm;
    ((uint4*)Xh)[off16] = ph.v;
    ((uint4*)Xl)[off16] = pl.v;
}

// top-2 helpers WITHOUT index tie-break (ties are masked by the ratio test);
// strict '>' keeps the earlier (lower-index) entry.
__device__ __forceinline__ void ins2v(float v, int i, float& b0, float& b1, int& i0, int& i1) {
    bool g0 = v > b0;
    bool g1 = v > b1;
    float nb1 = g0 ? b0 : (g1 ? v : b1);
    int   ni1 = g0 ? i0 : (g1 ? i : i1);
    b0 = g0 ? v : b0;
    i0 = g0 ? i : i0;
    b1 = nb1; i1 = ni1;
}
__device__ __forceinline__ void mrg2v(float& a0, float& a1, int& ai0, int& ai1,
                                      float b0, float b1, int bi0, int bi1) {
    bool f = b0 > a0;
    float n0 = f ? b0 : a0; int n0i = f ? bi0 : ai0;
    float s1 = f ? a0 : b0; int s1i = f ? ai0 : bi0;
    float s2 = f ? b1 : a1; int s2i = f ? bi1 : ai1;
    bool h = s2 > s1;
    a0 = n0; ai0 = n0i;
    a1 = h ? s2 : s1; ai1 = h ? s2i : s1i;
}

// MFMA GEMM (fp16 split, Keff=768) + fused both-direction top-2.
// 16 waves/block (1024 thr) = two 128-row halves (sub = w>>3) x 8-wave geometry.
// SINGLE 64x32 tile per wave (spill-free at the allocator's 64-VGPR cap, r23
// verified: FETCH 52MB/WRITE 27MB).  THIS ROUND: sbuf stride 20 -> 18 floats
// ([16][64][18] = 73,728 B) so TWO blocks fit in the 160KB LDS -> 32 waves/CU.
// Row scan becomes 16 scalar ds_read_b32 (same j-ascending order, identical
// top-2 semantics; 4-way bank conflicts on both scans, hidden by 2x waves).
// Barrier-free; col partials direct to global.  Requires n % 8192 == 0.
__global__ __launch_bounds__(1024)
void mfma_top2_16w(
    const ushort_t* __restrict__ Ah, const ushort_t* __restrict__ Al6,
    const ushort_t* __restrict__ Bh, const ushort_t* __restrict__ Bl6,
    const float* __restrict__ invA, const float* __restrict__ invB,
    float4* __restrict__ rowPart, float4* __restrict__ colPart, int n) {
    __shared__ float sbuf[16][64][18];    // 73,728 B -> 2 blocks/CU

    const int t = threadIdx.x, lane = t & 63, w = t >> 6;   // w 0..15
    const int sub = w >> 3, v = w & 7;
    const int wm = v & 1, wn = v >> 1;                       // wn 0..3
    const int lm = lane & 15, g = lane >> 4;
    const int bx = blockIdx.x, s = blockIdx.y;
    const int bxold = bx * 2 + sub;
    const int m0 = bxold * 128;
    const int NXT2 = (n >> 7) * 2;
    const int chunk = n / FNS;
    const int jbeg = s * chunk;
    const int NJT = chunk >> 7;

    // running row top-2: lane L owns row m0 + wm*64 + L (this wave's wn quarter)
    float rr0 = -INFINITY, rr1 = -INFINITY; int rri0 = -1, rri1 = -1;

    // epilogue for one 64x32 tile held in acc, at column base jt  (barrier-free)
    auto epilogue = [&](f32x4 (&acc)[4][2], int jt) {
        float rB[2];
#pragma unroll
        for (int fn = 0; fn < 2; ++fn) rB[fn] = invB[jt + wn * 32 + fn * 16 + lm];
        float rav[4][4];
#pragma unroll
        for (int fm = 0; fm < 4; ++fm) {
            float4 ra = *reinterpret_cast<const float4*>(&invA[m0 + wm * 64 + fm * 16 + g * 4]);
            rav[fm][0] = ra.x; rav[fm][1] = ra.y; rav[fm][2] = ra.z; rav[fm][3] = ra.w;
        }
#pragma unroll
        for (int h = 0; h < 2; ++h) {
            asm volatile("" ::: "memory");
#pragma unroll
            for (int fm = 0; fm < 4; ++fm)
#pragma unroll
                for (int r = 0; r < 4; ++r)
                    sbuf[w][fm * 16 + g * 4 + r][lm] =
                        acc[fm][h][r] * rav[fm][r] * rB[h];
            asm volatile("" ::: "memory");
            // row scan: lane L scans its row scalar, j ascending (16 values)
            {
                float b0 = -INFINITY, b1 = -INFINITY; int i0 = -1, i1 = -1;
                const int cb = jt + wn * 32 + h * 16;
#pragma unroll
                for (int j = 0; j < 16; ++j)
                    ins2v(sbuf[w][lane][j], cb + j, b0, b1, i0, i1);
                mrg2v(rr0, rr1, rri0, rri1, b0, b1, i0, i1);
            }
            // col scan: group q=g scans rows q*16..q*16+15 of col lm, then
            // shfl_xor(16)+shfl_xor(32) merges; lanes<16 write DIRECT to global
            {
                float b0 = -INFINITY, b1 = -INFINITY; int i0 = -1, i1 = -1;
#pragma unroll
                for (int r = 0; r < 16; ++r)
                    ins2v(sbuf[w][g * 16 + r][lm], m0 + wm * 64 + g * 16 + r, b0, b1, i0, i1);
                float o0 = __shfl_xor(b0, 16), o1 = __shfl_xor(b1, 16);
                int oi0 = __shfl_xor(i0, 16), oi1 = __shfl_xor(i1, 16);
                mrg2v(b0, b1, i0, i1, o0, o1, oi0, oi1);
                o0 = __shfl_xor(b0, 32); o1 = __shfl_xor(b1, 32);
                oi0 = __shfl_xor(i0, 32); oi1 = __shfl_xor(i1, 32);
                mrg2v(b0, b1, i0, i1, o0, o1, oi0, oi1);
                if (lane < 16)
                    colPart[(size_t)(jt + wn * 32 + h * 16 + lane) * NXT2 + bxold * 2 + wm] =
                        make_float4(b0, b1, (float)i0, (float)i1);
            }
        }
    };

    for (int ji = 0; ji < NJT; ++ji) {
        const int jt0 = jbeg + ji * 128;
        const int jcb0 = jt0 >> 7;
        f32x4 acc[4][2];
#pragma unroll
        for (int fm = 0; fm < 4; ++fm)
#pragma unroll
            for (int fn = 0; fn < 2; ++fn)
                acc[fm][fn] = f32x4{0.f, 0.f, 0.f, 0.f};

#pragma unroll 1
        for (int sk = 0; sk < 8; ++sk) {
            const size_t aoff = ((((size_t)bxold * 8 + sk) * 8 + wm * 4) * 64 + lane) * 8;
            const size_t bo = ((((size_t)jcb0 * 8 + sk) * 8 + wn * 2) * 64 + lane) * 8;
            // B fragments once per slab (16 VGPR)
            f16x8 bh[2], bl[2];
            bh[0] = *(const f16x8*)(Bh  + bo);
            bh[1] = *(const f16x8*)(Bh  + bo + 512);
            bl[0] = *(const f16x8*)(Bl6 + bo);
            bl[1] = *(const f16x8*)(Bl6 + bo + 512);
            bl[0] = bl[0] * (_Float16)0.015625f;
            bl[1] = bl[1] * (_Float16)0.015625f;
            // A fragments in two fm-halves (16 VGPR live at a time)
#pragma unroll
            for (int fmh = 0; fmh < 2; ++fmh) {
                f16x8 ah[2], al[2];
#pragma unroll
                for (int f = 0; f < 2; ++f) {
                    ah[f] = *(const f16x8*)(Ah  + aoff + (size_t)(fmh * 2 + f) * 512);
                    al[f] = *(const f16x8*)(Al6 + aoff + (size_t)(fmh * 2 + f) * 512);
                }
#pragma unroll
                for (int f = 0; f < 2; ++f) al[f] = al[f] * (_Float16)0.015625f;
#pragma unroll
                for (int f = 0; f < 2; ++f) {
                    const int fm = fmh * 2 + f;
#pragma unroll
                    for (int fn = 0; fn < 2; ++fn) {
                        acc[fm][fn] = __builtin_amdgcn_mfma_f32_16x16x32_f16(
                            ah[f], bh[fn], acc[fm][fn], 0, 0, 0);
                        acc[fm][fn] = __builtin_amdgcn_mfma_f32_16x16x32_f16(
                            al[f], bh[fn], acc[fm][fn], 0, 0, 0);
                        acc[fm][fn] = __builtin_amdgcn_mfma_f32_16x16x32_f16(
                            ah[f], bl[fn], acc[fm][fn], 0, 0, 0);
                    }
                }
            }
        }

        epilogue(acc, jt0);   // ascending j preserved
    }

    // final row merge: each sub-half merges its 4 wn quarters (sbuf as scratch)
    __syncthreads();
    float4* rowm = (float4*)&sbuf[0][0][0];   // [2][4][128] float4 = 16 KB
    rowm[sub * 512 + wn * 128 + wm * 64 + lane] =
        make_float4(rr0, rr1, (float)rri0, (float)rri1);
    __syncthreads();
    if (t < 256) {
        const int sr = t >> 7, lr = t & 127;
        float a0 = -INFINITY, a1 = -INFINITY; int ai0 = -1, ai1 = -1;
#pragma unroll
        for (int q = 0; q < 4; ++q) {
            float4 p = rowm[sr * 512 + q * 128 + lr];
            mrg2v(a0, a1, ai0, ai1, p.x, p.y, (int)p.z, (int)p.w);
        }
        rowPart[(size_t)(bx * 256 + t) * FNS + s] = make_float4(a0, a1, (float)ai0, (float)ai1);
    }
}

// ---- helpers with float-idx (used by merge/match + fallback) ----
__device__ __forceinline__ bool bt(float v, int i, float u, int j) {
    return v > u || (v == u && i < j);
}
__device__ __forceinline__ void mrg2(float& a0, int& ai0, float& a1, int& ai1,
                                     float b0, int bi0, float b1, int bi1) {
    if (bt(b0, bi0, a0, ai0)) {
        bool keepA0 = bt(a0, ai0, b1, bi1);
        float n1 = keepA0 ? a0 : b1; int ni1 = keepA0 ? ai0 : bi1;
        a0 = b0; ai0 = bi0; a1 = n1; ai1 = ni1;
    } else if (bt(b0, bi0, a1, ai1)) {
        a1 = b0; ai1 = bi0;
    }
}

// fused merge: i<n merges rowPart (cntR entries) -> tAB; i>=n merges colPart
// (cntC entries) -> tBA.  Per-element logic identical to the verified merge_part.
__global__ void merge2_kernel(const float4* __restrict__ rowPart, int cntR,
                              const float4* __restrict__ colPart, int cntC,
                              float4* __restrict__ tAB, float4* __restrict__ tBA, int n) {
    int i = blockIdx.x * blockDim.x + threadIdx.x;
    if (i >= 2 * n) return;
    const float4* part = (i < n) ? rowPart : colPart;
    float4* out = (i < n) ? tAB : tBA;
    int c = (i < n) ? i : i - n;
    int cnt = (i < n) ? cntR : cntC;
    float a0 = -INFINITY, a1 = -INFINITY; int ai0 = -1, ai1 = -1;
    for (int s = 0; s < cnt; ++s) {
        float4 p = part[(size_t)c * cnt + s];
        mrg2(a0, ai0, a1, ai1, p.x, (int)p.z, p.y, (int)p.w);
    }
    out[c] = make_float4(a0, a1, (float)ai0, (float)ai1);
}

__global__ void merge_part(const float4* __restrict__ part, float4* __restrict__ out,
                           int n, int cnt) {
    int i = blockIdx.x * blockDim.x + threadIdx.x;
    if (i >= n) return;
    float a0 = -INFINITY, a1 = -INFINITY; int ai0 = -1, ai1 = -1;
    for (int s = 0; s < cnt; ++s) {
        float4 p = part[(size_t)i * cnt + s];
        mrg2(a0, ai0, a1, ai1, p.x, (int)p.z, p.y, (int)p.w);
    }
    out[i] = make_float4(a0, a1, (float)ai0, (float)ai1);
}

__global__ void match_kernel(const float4* __restrict__ tAB,
                             const float4* __restrict__ tBA,
                             float* __restrict__ out, int n) {
    int i = blockIdx.x * blockDim.x + threadIdx.x;
    if (i >= n) return;
    float4 a = tAB[i];
    int j0 = (int)a.z;
    float d0 = 2.0f - 2.0f * a.x;
    float d1 = 2.0f - 2.0f * a.y;
    float r12 = d0 / (d1 + EPS_T);
    float4 b = tBA[j0];
    int nn21 = (int)b.z;
    float e0 = 2.0f - 2.0f * b.x;
    float e1 = 2.0f - 2.0f * b.y;
    float r21 = e0 / (e1 + EPS_T);
    bool m = (i == nn21) && (r12 <= RATIO_T) && (r21 <= RATIO_T);
    out[2 * i]     = m ? (float)i  : -1.0f;
    out[2 * i + 1] = m ? (float)j0 : -1.0f;
    out[2 * (size_t)n + i] = m ? a.x : 0.0f;
    out[3 * (size_t)n + i] = m ? 1.0f : 0.0f;
}

// ---------------- round-2 fused fp32 kernel (fallback) ----------------
__global__ void norms_kernel(const float* __restrict__ X, float* __restrict__ inv, int n) {
    int i = blockIdx.x * blockDim.x + threadIdx.x;
    if (i >= n) return;
    float s = 0.f;
#pragma unroll 8
    for (int k = 0; k < KDIM; ++k) {
        float v = X[(size_t)k * n + i];
        s += v * v;
    }
    inv[i] = 1.0f / sqrtf(s);
}

__device__ __forceinline__ void ins2f(float& a0, int& ai0, float& a1, int& ai1, float v, int i) {
    if (bt(v, i, a0, ai0)) { a1 = a0; ai1 = ai0; a0 = v; ai0 = i; }
    else if (bt(v, i, a1, ai1)) { a1 = v; ai1 = i; }
}

__global__ __launch_bounds__(256, 2) void gemm_both_top2(
    const float* __restrict__ A, const float* __restrict__ B,
    const float* __restrict__ invA, const float* __restrict__ invB,
    float4* __restrict__ rowPart, float4* __restrict__ colPart, int n) {
    __shared__ float As[FBK][FBM];
    __shared__ float Bs[FBK][FBN];
    __shared__ float4 colbuf2[4][FBN];

    const int t  = threadIdx.x;
    const int tx = t & 15, ty = t >> 4;
    const int bx = blockIdx.x, s = blockIdx.y;
    const int m0 = bx * FBM;
    const int NXT = n / FBM;
    const int chunk = n / FNS;
    const int jbeg = s * chunk;

    int rIdx[8]; float qinv[8];
#pragma unroll
    for (int ii = 0; ii < 8; ++ii) {
        int lr = (ii < 4) ? (ty * 4 + ii) : (64 + ty * 4 + ii - 4);
        rIdx[ii] = m0 + lr;
        qinv[ii] = invA[m0 + lr];
    }
    float rb0[8], rb1[8]; int ri0[8], ri1[8];
#pragma unroll
    for (int ii = 0; ii < 8; ++ii) { rb0[ii] = -INFINITY; rb1[ii] = -INFINITY; ri0[ii] = -1; ri1[ii] = -1; }

    const int r0 = t >> 5,          c0 = (t & 31) << 2;
    const int r1 = (t + 256) >> 5,  c1 = (t & 31) << 2;

    for (int jt = jbeg; jt < jbeg + chunk; jt += FBN) {
        float rinv[8]; int cIdx[8];
#pragma unroll
        for (int jj = 0; jj < 8; ++jj) {
            int lc = (jj < 4) ? (tx * 4 + jj) : (64 + tx * 4 + jj - 4);
            cIdx[jj] = jt + lc;
            rinv[jj] = invB[jt + lc];
        }
        float acc[8][8];
#pragma unroll
        for (int ii = 0; ii < 8; ++ii)
#pragma unroll
            for (int jj = 0; jj < 8; ++jj) acc[ii][jj] = 0.f;

        for (int k0 = 0; k0 < KDIM; k0 += FBK) {
            float4 ga0 = *reinterpret_cast<const float4*>(&A[(size_t)(k0 + r0) * n + m0 + c0]);
            float4 ga1 = *reinterpret_cast<const float4*>(&A[(size_t)(k0 + r1) * n + m0 + c1]);
            float4 gb0 = *reinterpret_cast<const float4*>(&B[(size_t)(k0 + r0) * n + jt + c0]);
            float4 gb1 = *reinterpret_cast<const float4*>(&B[(size_t)(k0 + r1) * n + jt + c1]);
            __syncthreads();
            *reinterpret_cast<float4*>(&As[r0][c0]) = ga0;
            *reinterpret_cast<float4*>(&As[r1][c1]) = ga1;
            *reinterpret_cast<float4*>(&Bs[r0][c0]) = gb0;
            *reinterpret_cast<float4*>(&Bs[r1][c1]) = gb1;
            __syncthreads();
#pragma unroll
            for (int k = 0; k < BKS; ++k) {
                float4 a0 = *reinterpret_cast<const float4*>(&As[k][ty * 4]);
                float4 a1 = *reinterpret_cast<const float4*>(&As[k][64 + ty * 4]);
                float4 b0 = *reinterpret_cast<const float4*>(&Bs[k][tx * 4]);
                float4 b1 = *reinterpret_cast<const float4*>(&Bs[k][64 + tx * 4]);
                float av[8] = {a0.x, a0.y, a0.z, a0.w, a1.x, a1.y, a1.z, a1.w};
                float bv[8] = {b0.x, b0.y, b0.z, b0.w, b1.x, b1.y, b1.z, b1.w};
#pragma unroll
                for (int ii = 0; ii < 8; ++ii)
#pragma unroll
                    for (int jj = 0; jj < 8; ++jj) acc[ii][jj] += av[ii] * bv[jj];
            }
        }
#pragma unroll
        for (int ii = 0; ii < 8; ++ii)
#pragma unroll
            for (int jj = 0; jj < 8; ++jj) acc[ii][jj] = acc[ii][jj] * qinv[ii] * rinv[jj];

#pragma unroll
        for (int ii = 0; ii < 8; ++ii) {
            float b0 = -INFINITY, b1 = -INFINITY; int i0 = -1, i1 = -1;
#pragma unroll
            for (int jj = 0; jj < 8; ++jj) ins2f(b0, i0, b1, i1, acc[ii][jj], cIdx[jj]);
#pragma unroll
            for (int m = 1; m <= 8; m <<= 1) {
                float o0 = __shfl_xor(b0, m), o1 = __shfl_xor(b1, m);
                int oi0 = __shfl_xor(i0, m), oi1 = __shfl_xor(i1, m);
                mrg2(b0, i0, b1, i1, o0, oi0, o1, oi1);
            }
            mrg2(rb0[ii], ri0[ii], rb1[ii], ri1[ii], b0, i0, b1, i1);
        }

#pragma unroll
        for (int jj = 0; jj < 8; ++jj) {
            float b0 = -INFINITY, b1 = -INFINITY; int i0 = -1, i1 = -1;
#pragma unroll
            for (int ii = 0; ii < 8; ++ii) ins2f(b0, i0, b1, i1, acc[ii][jj], rIdx[ii]);
#pragma unroll
            for (int m = 16; m <= 32; m <<= 1) {
                float o0 = __shfl_xor(b0, m), o1 = __shfl_xor(b1, m);
                int oi0 = __shfl_xor(i0, m), oi1 = __shfl_xor(i1, m);
                mrg2(b0, i0, b1, i1, o0, oi0, o1, oi1);
            }
            if ((t & 48) == 0) {
                int lc = (jj < 4) ? (tx * 4 + jj) : (64 + tx * 4 + jj - 4);
                colbuf2[t >> 6][lc] = make_float4(b0, b1, (float)i0, (float)i1);
            }
        }
        __syncthreads();
        if (t < FBN) {
            float a0 = -INFINITY, a1 = -INFINITY; int ai0 = -1, ai1 = -1;
#pragma unroll
            for (int ww = 0; ww < 4; ++ww) {
                float4 p = colbuf2[ww][t];
                mrg2(a0, ai0, a1, ai1, p.x, (int)p.z, p.y, (int)p.w);
            }
            colPart[(size_t)(jt + t) * NXT + bx] = make_float4(a0, a1, (float)ai0, (float)ai1);
        }
        __syncthreads();
    }
    if (tx == 0) {
#pragma unroll
        for (int ii = 0; ii < 8; ++ii)
            rowPart[(size_t)rIdx[ii] * FNS + s] =
                make_float4(rb0[ii], rb1[ii], (float)ri0[ii], (float)ri1[ii]);
    }
}

extern "C" void kernel_launch(void* const* d_in, const int* in_sizes, int n_in,
                              void* d_out, int out_size, void* d_ws, size_t ws_size,
                              hipStream_t stream) {
    const float* A = (const float*)d_in[0];
    const float* B = (const float*)d_in[1];
    const int n = in_sizes[0] / KDIM;   // 8192

    dim3 blk(256);
    dim3 ngrid((n + 255) / 256);
    const int NXT = n / 128;

    // MFMA-path workspace requirement; needs n % 8192 == 0 (256-row blocks)
    size_t needM = (size_t)n * 4 * 2                 // invA, invB
                 + (size_t)n * 512 * 4               // Ah, Al6, Bh, Bl6 (fp16, frag-order)
                 + (size_t)n * FNS * 16              // rowPart
                 + (size_t)n * (NXT * 2) * 16        // colPart (per (bxold, wm) slot)
                 + (size_t)n * 16 * 2;               // tAB, tBA
    bool mfma_ok = (n % 8192 == 0) && (ws_size >= needM);

    if (mfma_ok) {
        char* p = (char*)d_ws;
        float* invA = (float*)p;       p += (size_t)n * 4;
        float* invB = (float*)p;       p += (size_t)n * 4;
        ushort_t* Ah  = (ushort_t*)p;  p += (size_t)n * 512;
        ushort_t* Al6 = (ushort_t*)p;  p += (size_t)n * 512;
        ushort_t* Bh  = (ushort_t*)p;  p += (size_t)n * 512;
        ushort_t* Bl6 = (ushort_t*)p;  p += (size_t)n * 512;
        float4* rowPart = (float4*)p;  p += (size_t)n * FNS * 16;
        float4* colPart = (float4*)p;  p += (size_t)n * (NXT * 2) * 16;
        float4* tAB = (float4*)p;      p += (size_t)n * 16;
        float4* tBA = (float4*)p;

        dim3 n2grid((2 * n + 255) / 256);
        norms2_kernel<<<n2grid, blk, 0, stream>>>(A, B, invA, invB, n);
        dim3 s2grid((2 * n * 32 + 255) / 256);
        split2_kernel<<<s2grid, blk, 0, stream>>>(A, B, Ah, Al6, Bh, Bl6, n);

        dim3 grid(n / 256, FNS);
        dim3 blk1024(1024);
        mfma_top2_16w<<<grid, blk1024, 0, stream>>>(Ah, Al6, Bh, Bl6, invA, invB,
                                                    rowPart, colPart, n);

        merge2_kernel<<<n2grid, blk, 0, stream>>>(rowPart, FNS, colPart, NXT * 2,
                                                  tAB, tBA, n);
        match_kernel<<<ngrid, blk, 0, stream>>>(tAB, tBA, (float*)d_out, n);
    } else {
        // fallback: round-2 verified fused fp32 path
        float* ws = (float*)d_ws;
        float* invA = ws;
        float* invB = ws + n;
        float4* rowPart = (float4*)(ws + 2 * (size_t)n);
        float4* colPart = rowPart + (size_t)n * FNS;
        float4* tAB     = colPart + (size_t)n * (n / FBM);
        float4* tBA     = tAB + n;

        norms_kernel<<<ngrid, blk, 0, stream>>>(A, invA, n);
        norms_kernel<<<ngrid, blk, 0, stream>>>(B, invB, n);
        dim3 grid(n / FBM, FNS);
        gemm_both_top2<<<grid, blk, 0, stream>>>(A, B, invA, invB, rowPart, colPart, n);
        merge_part<<<ngrid, blk, 0, stream>>>(rowPart, tAB, n, FNS);
        merge_part<<<ngrid, blk, 0, stream>>>(colPart, tBA, n, n / FBM);
        match_kernel<<<ngrid, blk, 0, stream>>>(tAB, tBA, (float*)d_out, n);
    }
}

// Round 25
// 198.636 us; speedup vs baseline: 1.0123x; 1.0123x over previous
//
#include <hip/hip_runtime.h>
#include <hip/hip_bf16.h>
#include <math.h>

#define KDIM 256
#define RATIO_T 0.9f
#define EPS_T 1e-8f
#define FNS 16

// fallback geometry (round-2 verified)
#define FBM 128
#define FBN 128
#define FBK 16
#define BM 64
#define BN 64
#define BKS 16

typedef _Float16 f16x8 __attribute__((ext_vector_type(8)));
typedef float f32x4 __attribute__((ext_vector_type(4)));
typedef unsigned short ushort_t;

// 1 / ||column i|| for TWO matrices in one launch: i<n -> A, else B.
__global__ void norms2_kernel(const float* __restrict__ A, const float* __restrict__ B,
                              float* __restrict__ invA, float* __restrict__ invB, int n) {
    int i = blockIdx.x * blockDim.x + threadIdx.x;
    if (i >= 2 * n) return;
    const float* X = (i < n) ? A : B;
    float* out = (i < n) ? invA : invB;
    int c = (i < n) ? i : i - n;
    float s = 0.f;
#pragma unroll 8
    for (int k = 0; k < KDIM; ++k) {
        float v = X[(size_t)k * n + c];
        s += v * v;
    }
    out[c] = 1.0f / sqrtf(s);
}

// fp16 split for TWO matrices in one launch (first half A, second half B).
// frag layout: 16B unit index = ((bm*8 + s)*8 + fm)*64 + g*16 + lm
__global__ void split2_kernel(const float* __restrict__ A, const float* __restrict__ B,
                              ushort_t* __restrict__ Ahh, ushort_t* __restrict__ Al6,
                              ushort_t* __restrict__ Bhh, ushort_t* __restrict__ Bl6, int n) {
    int tid = blockIdx.x * blockDim.x + threadIdx.x;   // 2*n*32 threads total
    int half = (tid >= n * 32) ? 1 : 0;
    int t2 = tid - half * n * 32;
    const float* X = half ? B : A;
    ushort_t* Xh = half ? Bhh : Ahh;
    ushort_t* Xl = half ? Bl6 : Al6;
    int lane = t2 & 63;
    int rest = t2 >> 6;
    int kg = rest & 31, iblk = rest >> 5;
    int i = iblk * 64 + lane;
    if (i >= n) return;
    float x[8];
#pragma unroll
    for (int e = 0; e < 8; ++e) x[e] = X[(size_t)(kg * 8 + e) * n + i];
    union { ushort_t us[8]; uint4 v; } ph, pl;
#pragma unroll
    for (int e = 0; e < 8; ++e) {
        _Float16 hh = (_Float16)x[e];
        float r = x[e] - (float)hh;
        _Float16 ll = (_Float16)(r * 64.0f);
        ph.us[e] = __builtin_bit_cast(ushort_t, hh);
        pl.us[e] = __builtin_bit_cast(ushort_t, ll);
    }
    int bm = i >> 7, fm = (i >> 4) & 7, lmm = i & 15;
    int sk = kg >> 2, gg = kg & 3;
    size_t off16 = ((((size_t)bm * 8 + sk) * 8 + fm) * 64) + gg * 16 + lmm;
    ((uint4*)Xh)[off16] = ph.v;
    ((uint4*)Xl)[off16] = pl.v;
}

// top-2 helpers WITHOUT index tie-break (ties are masked by the ratio test);
// strict '>' keeps the earlier (lower-index) entry.
__device__ __forceinline__ void ins2v(float v, int i, float& b0, float& b1, int& i0, int& i1) {
    bool g0 = v > b0;
    bool g1 = v > b1;
    float nb1 = g0 ? b0 : (g1 ? v : b1);
    int   ni1 = g0 ? i0 : (g1 ? i : i1);
    b0 = g0 ? v : b0;
    i0 = g0 ? i : i0;
    b1 = nb1; i1 = ni1;
}
__device__ __forceinline__ void mrg2v(float& a0, float& a1, int& ai0, int& ai1,
                                      float b0, float b1, int bi0, int bi1) {
    bool f = b0 > a0;
    float n0 = f ? b0 : a0; int n0i = f ? bi0 : ai0;
    float s1 = f ? a0 : b0; int s1i = f ? ai0 : bi0;
    float s2 = f ? b1 : a1; int s2i = f ? bi1 : ai1;
    bool h = s2 > s1;
    a0 = n0; ai0 = n0i;
    a1 = h ? s2 : s1; ai1 = h ? s2i : s1i;
}

// MFMA GEMM (fp16 split, Keff=768) + fused both-direction top-2.
// 16 waves/block (1024 thr) = two 128-row halves (sub = w>>3) x 8-wave geometry.
// SINGLE 64x32 tile per wave per j-step with fm-split A loads: spill-free at
// the allocator's hard 64-VGPR cap (r23 verified: FETCH 52MB, WRITE 27MB).
// Barrier-free main loop; col partials direct to global (slot (bx*2+sub)*2+wm).
// This is the verified round-23 configuration (best total: 199.09 us).
// Requires n % 8192 == 0.
__global__ __launch_bounds__(1024)
__attribute__((amdgpu_waves_per_eu(4, 4)))
void mfma_top2_16w(
    const ushort_t* __restrict__ Ah, const ushort_t* __restrict__ Al6,
    const ushort_t* __restrict__ Bh, const ushort_t* __restrict__ Bl6,
    const float* __restrict__ invA, const float* __restrict__ invB,
    float4* __restrict__ rowPart, float4* __restrict__ colPart, int n) {
    __shared__ float sbuf[16][64][20];    // 81,920 B (per-wave private tiles)

    const int t = threadIdx.x, lane = t & 63, w = t >> 6;   // w 0..15
    const int sub = w >> 3, v = w & 7;
    const int wm = v & 1, wn = v >> 1;                       // wn 0..3
    const int lm = lane & 15, g = lane >> 4;
    const int bx = blockIdx.x, s = blockIdx.y;
    const int bxold = bx * 2 + sub;
    const int m0 = bxold * 128;
    const int NXT2 = (n >> 7) * 2;
    const int chunk = n / FNS;
    const int jbeg = s * chunk;
    const int NJT = chunk >> 7;

    // running row top-2: lane L owns row m0 + wm*64 + L (this wave's wn quarter)
    float rr0 = -INFINITY, rr1 = -INFINITY; int rri0 = -1, rri1 = -1;

    // epilogue for one 64x32 tile held in acc, at column base jt  (barrier-free)
    auto epilogue = [&](f32x4 (&acc)[4][2], int jt) {
        float rB[2];
#pragma unroll
        for (int fn = 0; fn < 2; ++fn) rB[fn] = invB[jt + wn * 32 + fn * 16 + lm];
        float rav[4][4];
#pragma unroll
        for (int fm = 0; fm < 4; ++fm) {
            float4 ra = *reinterpret_cast<const float4*>(&invA[m0 + wm * 64 + fm * 16 + g * 4]);
            rav[fm][0] = ra.x; rav[fm][1] = ra.y; rav[fm][2] = ra.z; rav[fm][3] = ra.w;
        }
#pragma unroll
        for (int h = 0; h < 2; ++h) {
            asm volatile("" ::: "memory");
#pragma unroll
            for (int fm = 0; fm < 4; ++fm)
#pragma unroll
                for (int r = 0; r < 4; ++r)
                    sbuf[w][fm * 16 + g * 4 + r][lm] =
                        acc[fm][h][r] * rav[fm][r] * rB[h];
            asm volatile("" ::: "memory");
            // row scan: lane L reads its row as 4 x float4 (16B-aligned, stride 80B)
            {
                float b0 = -INFINITY, b1 = -INFINITY; int i0 = -1, i1 = -1;
                const int cb = jt + wn * 32 + h * 16;
                const float4* rowp = reinterpret_cast<const float4*>(&sbuf[w][lane][0]);
#pragma unroll
                for (int qd = 0; qd < 4; ++qd) {
                    float4 vv = rowp[qd];
                    ins2v(vv.x, cb + qd * 4 + 0, b0, b1, i0, i1);
                    ins2v(vv.y, cb + qd * 4 + 1, b0, b1, i0, i1);
                    ins2v(vv.z, cb + qd * 4 + 2, b0, b1, i0, i1);
                    ins2v(vv.w, cb + qd * 4 + 3, b0, b1, i0, i1);
                }
                mrg2v(rr0, rr1, rri0, rri1, b0, b1, i0, i1);
            }
            // col scan: group q=g scans rows q*16..q*16+15 of col lm, then
            // shfl_xor(16)+shfl_xor(32) merges; lanes<16 write DIRECT to global
            {
                float b0 = -INFINITY, b1 = -INFINITY; int i0 = -1, i1 = -1;
#pragma unroll
                for (int r = 0; r < 16; ++r)
                    ins2v(sbuf[w][g * 16 + r][lm], m0 + wm * 64 + g * 16 + r, b0, b1, i0, i1);
                float o0 = __shfl_xor(b0, 16), o1 = __shfl_xor(b1, 16);
                int oi0 = __shfl_xor(i0, 16), oi1 = __shfl_xor(i1, 16);
                mrg2v(b0, b1, i0, i1, o0, o1, oi0, oi1);
                o0 = __shfl_xor(b0, 32); o1 = __shfl_xor(b1, 32);
                oi0 = __shfl_xor(i0, 32); oi1 = __shfl_xor(i1, 32);
                mrg2v(b0, b1, i0, i1, o0, o1, oi0, oi1);
                if (lane < 16)
                    colPart[(size_t)(jt + wn * 32 + h * 16 + lane) * NXT2 + bxold * 2 + wm] =
                        make_float4(b0, b1, (float)i0, (float)i1);
            }
        }
    };

    for (int ji = 0; ji < NJT; ++ji) {
        const int jt0 = jbeg + ji * 128;
        const int jcb0 = jt0 >> 7;
        f32x4 acc[4][2];
#pragma unroll
        for (int fm = 0; fm < 4; ++fm)
#pragma unroll
            for (int fn = 0; fn < 2; ++fn)
                acc[fm][fn] = f32x4{0.f, 0.f, 0.f, 0.f};

#pragma unroll 1
        for (int sk = 0; sk < 8; ++sk) {
            const size_t aoff = ((((size_t)bxold * 8 + sk) * 8 + wm * 4) * 64 + lane) * 8;
            const size_t bo = ((((size_t)jcb0 * 8 + sk) * 8 + wn * 2) * 64 + lane) * 8;
            // B fragments once per slab (16 VGPR)
            f16x8 bh[2], bl[2];
            bh[0] = *(const f16x8*)(Bh  + bo);
            bh[1] = *(const f16x8*)(Bh  + bo + 512);
            bl[0] = *(const f16x8*)(Bl6 + bo);
            bl[1] = *(const f16x8*)(Bl6 + bo + 512);
            bl[0] = bl[0] * (_Float16)0.015625f;
            bl[1] = bl[1] * (_Float16)0.015625f;
            // A fragments in two fm-halves (16 VGPR live at a time)
#pragma unroll
            for (int fmh = 0; fmh < 2; ++fmh) {
                f16x8 ah[2], al[2];
#pragma unroll
                for (int f = 0; f < 2; ++f) {
                    ah[f] = *(const f16x8*)(Ah  + aoff + (size_t)(fmh * 2 + f) * 512);
                    al[f] = *(const f16x8*)(Al6 + aoff + (size_t)(fmh * 2 + f) * 512);
                }
#pragma unroll
                for (int f = 0; f < 2; ++f) al[f] = al[f] * (_Float16)0.015625f;
#pragma unroll
                for (int f = 0; f < 2; ++f) {
                    const int fm = fmh * 2 + f;
#pragma unroll
                    for (int fn = 0; fn < 2; ++fn) {
                        acc[fm][fn] = __builtin_amdgcn_mfma_f32_16x16x32_f16(
                            ah[f], bh[fn], acc[fm][fn], 0, 0, 0);
                        acc[fm][fn] = __builtin_amdgcn_mfma_f32_16x16x32_f16(
                            al[f], bh[fn], acc[fm][fn], 0, 0, 0);
                        acc[fm][fn] = __builtin_amdgcn_mfma_f32_16x16x32_f16(
                            ah[f], bl[fn], acc[fm][fn], 0, 0, 0);
                    }
                }
            }
        }

        epilogue(acc, jt0);   // ascending j preserved
    }

    // final row merge: each sub-half merges its 4 wn quarters (sbuf as scratch)
    __syncthreads();
    float4* rowm = (float4*)&sbuf[0][0][0];   // [2][4][128] float4 = 16 KB
    rowm[sub * 512 + wn * 128 + wm * 64 + lane] =
        make_float4(rr0, rr1, (float)rri0, (float)rri1);
    __syncthreads();
    if (t < 256) {
        const int sr = t >> 7, lr = t & 127;
        float a0 = -INFINITY, a1 = -INFINITY; int ai0 = -1, ai1 = -1;
#pragma unroll
        for (int q = 0; q < 4; ++q) {
            float4 p = rowm[sr * 512 + q * 128 + lr];
            mrg2v(a0, a1, ai0, ai1, p.x, p.y, (int)p.z, (int)p.w);
        }
        rowPart[(size_t)(bx * 256 + t) * FNS + s] = make_float4(a0, a1, (float)ai0, (float)ai1);
    }
}

// ---- helpers with float-idx (used by merge/match + fallback) ----
__device__ __forceinline__ bool bt(float v, int i, float u, int j) {
    return v > u || (v == u && i < j);
}
__device__ __forceinline__ void mrg2(float& a0, int& ai0, float& a1, int& ai1,
                                     float b0, int bi0, float b1, int bi1) {
    if (bt(b0, bi0, a0, ai0)) {
        bool keepA0 = bt(a0, ai0, b1, bi1);
        float n1 = keepA0 ? a0 : b1; int ni1 = keepA0 ? ai0 : bi1;
        a0 = b0; ai0 = bi0; a1 = n1; ai1 = ni1;
    } else if (bt(b0, bi0, a1, ai1)) {
        a1 = b0; ai1 = bi0;
    }
}

// fused merge: i<n merges rowPart (cntR entries) -> tAB; i>=n merges colPart
// (cntC entries) -> tBA.  Per-element logic identical to the verified merge_part.
__global__ void merge2_kernel(const float4* __restrict__ rowPart, int cntR,
                              const float4* __restrict__ colPart, int cntC,
                              float4* __restrict__ tAB, float4* __restrict__ tBA, int n) {
    int i = blockIdx.x * blockDim.x + threadIdx.x;
    if (i >= 2 * n) return;
    const float4* part = (i < n) ? rowPart : colPart;
    float4* out = (i < n) ? tAB : tBA;
    int c = (i < n) ? i : i - n;
    int cnt = (i < n) ? cntR : cntC;
    float a0 = -INFINITY, a1 = -INFINITY; int ai0 = -1, ai1 = -1;
    for (int s = 0; s < cnt; ++s) {
        float4 p = part[(size_t)c * cnt + s];
        mrg2(a0, ai0, a1, ai1, p.x, (int)p.z, p.y, (int)p.w);
    }
    out[c] = make_float4(a0, a1, (float)ai0, (float)ai1);
}

__global__ void merge_part(const float4* __restrict__ part, float4* __restrict__ out,
                           int n, int cnt) {
    int i = blockIdx.x * blockDim.x + threadIdx.x;
    if (i >= n) return;
    float a0 = -INFINITY, a1 = -INFINITY; int ai0 = -1, ai1 = -1;
    for (int s = 0; s < cnt; ++s) {
        float4 p = part[(size_t)i * cnt + s];
        mrg2(a0, ai0, a1, ai1, p.x, (int)p.z, p.y, (int)p.w);
    }
    out[i] = make_float4(a0, a1, (float)ai0, (float)ai1);
}

__global__ void match_kernel(const float4* __restrict__ tAB,
                             const float4* __restrict__ tBA,
                             float* __restrict__ out, int n) {
    int i = blockIdx.x * blockDim.x + threadIdx.x;
    if (i >= n) return;
    float4 a = tAB[i];
    int j0 = (int)a.z;
    float d0 = 2.0f - 2.0f * a.x;
    float d1 = 2.0f - 2.0f * a.y;
    float r12 = d0 / (d1 + EPS_T);
    float4 b = tBA[j0];
    int nn21 = (int)b.z;
    float e0 = 2.0f - 2.0f * b.x;
    float e1 = 2.0f - 2.0f * b.y;
    float r21 = e0 / (e1 + EPS_T);
    bool m = (i == nn21) && (r12 <= RATIO_T) && (r21 <= RATIO_T);
    out[2 * i]     = m ? (float)i  : -1.0f;
    out[2 * i + 1] = m ? (float)j0 : -1.0f;
    out[2 * (size_t)n + i] = m ? a.x : 0.0f;
    out[3 * (size_t)n + i] = m ? 1.0f : 0.0f;
}

// ---------------- round-2 fused fp32 kernel (fallback) ----------------
__global__ void norms_kernel(const float* __restrict__ X, float* __restrict__ inv, int n) {
    int i = blockIdx.x * blockDim.x + threadIdx.x;
    if (i >= n) return;
    float s = 0.f;
#pragma unroll 8
    for (int k = 0; k < KDIM; ++k) {
        float v = X[(size_t)k * n + i];
        s += v * v;
    }
    inv[i] = 1.0f / sqrtf(s);
}

__device__ __forceinline__ void ins2f(float& a0, int& ai0, float& a1, int& ai1, float v, int i) {
    if (bt(v, i, a0, ai0)) { a1 = a0; ai1 = ai0; a0 = v; ai0 = i; }
    else if (bt(v, i, a1, ai1)) { a1 = v; ai1 = i; }
}

__global__ __launch_bounds__(256, 2) void gemm_both_top2(
    const float* __restrict__ A, const float* __restrict__ B,
    const float* __restrict__ invA, const float* __restrict__ invB,
    float4* __restrict__ rowPart, float4* __restrict__ colPart, int n) {
    __shared__ float As[FBK][FBM];
    __shared__ float Bs[FBK][FBN];
    __shared__ float4 colbuf2[4][FBN];

    const int t  = threadIdx.x;
    const int tx = t & 15, ty = t >> 4;
    const int bx = blockIdx.x, s = blockIdx.y;
    const int m0 = bx * FBM;
    const int NXT = n / FBM;
    const int chunk = n / FNS;
    const int jbeg = s * chunk;

    int rIdx[8]; float qinv[8];
#pragma unroll
    for (int ii = 0; ii < 8; ++ii) {
        int lr = (ii < 4) ? (ty * 4 + ii) : (64 + ty * 4 + ii - 4);
        rIdx[ii] = m0 + lr;
        qinv[ii] = invA[m0 + lr];
    }
    float rb0[8], rb1[8]; int ri0[8], ri1[8];
#pragma unroll
    for (int ii = 0; ii < 8; ++ii) { rb0[ii] = -INFINITY; rb1[ii] = -INFINITY; ri0[ii] = -1; ri1[ii] = -1; }

    const int r0 = t >> 5,          c0 = (t & 31) << 2;
    const int r1 = (t + 256) >> 5,  c1 = (t & 31) << 2;

    for (int jt = jbeg; jt < jbeg + chunk; jt += FBN) {
        float rinv[8]; int cIdx[8];
#pragma unroll
        for (int jj = 0; jj < 8; ++jj) {
            int lc = (jj < 4) ? (tx * 4 + jj) : (64 + tx * 4 + jj - 4);
            cIdx[jj] = jt + lc;
            rinv[jj] = invB[jt + lc];
        }
        float acc[8][8];
#pragma unroll
        for (int ii = 0; ii < 8; ++ii)
#pragma unroll
            for (int jj = 0; jj < 8; ++jj) acc[ii][jj] = 0.f;

        for (int k0 = 0; k0 < KDIM; k0 += FBK) {
            float4 ga0 = *reinterpret_cast<const float4*>(&A[(size_t)(k0 + r0) * n + m0 + c0]);
            float4 ga1 = *reinterpret_cast<const float4*>(&A[(size_t)(k0 + r1) * n + m0 + c1]);
            float4 gb0 = *reinterpret_cast<const float4*>(&B[(size_t)(k0 + r0) * n + jt + c0]);
            float4 gb1 = *reinterpret_cast<const float4*>(&B[(size_t)(k0 + r1) * n + jt + c1]);
            __syncthreads();
            *reinterpret_cast<float4*>(&As[r0][c0]) = ga0;
            *reinterpret_cast<float4*>(&As[r1][c1]) = ga1;
            *reinterpret_cast<float4*>(&Bs[r0][c0]) = gb0;
            *reinterpret_cast<float4*>(&Bs[r1][c1]) = gb1;
            __syncthreads();
#pragma unroll
            for (int k = 0; k < BKS; ++k) {
                float4 a0 = *reinterpret_cast<const float4*>(&As[k][ty * 4]);
                float4 a1 = *reinterpret_cast<const float4*>(&As[k][64 + ty * 4]);
                float4 b0 = *reinterpret_cast<const float4*>(&Bs[k][tx * 4]);
                float4 b1 = *reinterpret_cast<const float4*>(&Bs[k][64 + tx * 4]);
                float av[8] = {a0.x, a0.y, a0.z, a0.w, a1.x, a1.y, a1.z, a1.w};
                float bv[8] = {b0.x, b0.y, b0.z, b0.w, b1.x, b1.y, b1.z, b1.w};
#pragma unroll
                for (int ii = 0; ii < 8; ++ii)
#pragma unroll
                    for (int jj = 0; jj < 8; ++jj) acc[ii][jj] += av[ii] * bv[jj];
            }
        }
#pragma unroll
        for (int ii = 0; ii < 8; ++ii)
#pragma unroll
            for (int jj = 0; jj < 8; ++jj) acc[ii][jj] = acc[ii][jj] * qinv[ii] * rinv[jj];

#pragma unroll
        for (int ii = 0; ii < 8; ++ii) {
            float b0 = -INFINITY, b1 = -INFINITY; int i0 = -1, i1 = -1;
#pragma unroll
            for (int jj = 0; jj < 8; ++jj) ins2f(b0, i0, b1, i1, acc[ii][jj], cIdx[jj]);
#pragma unroll
            for (int m = 1; m <= 8; m <<= 1) {
                float o0 = __shfl_xor(b0, m), o1 = __shfl_xor(b1, m);
                int oi0 = __shfl_xor(i0, m), oi1 = __shfl_xor(i1, m);
                mrg2(b0, i0, b1, i1, o0, oi0, o1, oi1);
            }
            mrg2(rb0[ii], ri0[ii], rb1[ii], ri1[ii], b0, i0, b1, i1);
        }

#pragma unroll
        for (int jj = 0; jj < 8; ++jj) {
            float b0 = -INFINITY, b1 = -INFINITY; int i0 = -1, i1 = -1;
#pragma unroll
            for (int ii = 0; ii < 8; ++ii) ins2f(b0, i0, b1, i1, acc[ii][jj], rIdx[ii]);
#pragma unroll
            for (int m = 16; m <= 32; m <<= 1) {
                float o0 = __shfl_xor(b0, m), o1 = __shfl_xor(b1, m);
                int oi0 = __shfl_xor(i0, m), oi1 = __shfl_xor(i1, m);
                mrg2(b0, i0, b1, i1, o0, oi0, o1, oi1);
            }
            if ((t & 48) == 0) {
                int lc = (jj < 4) ? (tx * 4 + jj) : (64 + tx * 4 + jj - 4);
                colbuf2[t >> 6][lc] = make_float4(b0, b1, (float)i0, (float)i1);
            }
        }
        __syncthreads();
        if (t < FBN) {
            float a0 = -INFINITY, a1 = -INFINITY; int ai0 = -1, ai1 = -1;
#pragma unroll
            for (int ww = 0; ww < 4; ++ww) {
                float4 p = colbuf2[ww][t];
                mrg2(a0, ai0, a1, ai1, p.x, (int)p.z, p.y, (int)p.w);
            }
            colPart[(size_t)(jt + t) * NXT + bx] = make_float4(a0, a1, (float)ai0, (float)ai1);
        }
        __syncthreads();
    }
    if (tx == 0) {
#pragma unroll
        for (int ii = 0; ii < 8; ++ii)
            rowPart[(size_t)rIdx[ii] * FNS + s] =
                make_float4(rb0[ii], rb1[ii], (float)ri0[ii], (float)ri1[ii]);
    }
}

extern "C" void kernel_launch(void* const* d_in, const int* in_sizes, int n_in,
                              void* d_out, int out_size, void* d_ws, size_t ws_size,
                              hipStream_t stream) {
    const float* A = (const float*)d_in[0];
    const float* B = (const float*)d_in[1];
    const int n = in_sizes[0] / KDIM;   // 8192

    dim3 blk(256);
    dim3 ngrid((n + 255) / 256);
    const int NXT = n / 128;

    // MFMA-path workspace requirement; needs n % 8192 == 0 (256-row blocks)
    size_t needM = (size_t)n * 4 * 2                 // invA, invB
                 + (size_t)n * 512 * 4               // Ah, Al6, Bh, Bl6 (fp16, frag-order)
                 + (size_t)n * FNS * 16              // rowPart
                 + (size_t)n * (NXT * 2) * 16        // colPart (per (bxold, wm) slot)
                 + (size_t)n * 16 * 2;               // tAB, tBA
    bool mfma_ok = (n % 8192 == 0) && (ws_size >= needM);

    if (mfma_ok) {
        char* p = (char*)d_ws;
        float* invA = (float*)p;       p += (size_t)n * 4;
        float* invB = (float*)p;       p += (size_t)n * 4;
        ushort_t* Ah  = (ushort_t*)p;  p += (size_t)n * 512;
        ushort_t* Al6 = (ushort_t*)p;  p += (size_t)n * 512;
        ushort_t* Bh  = (ushort_t*)p;  p += (size_t)n * 512;
        ushort_t* Bl6 = (ushort_t*)p;  p += (size_t)n * 512;
        float4* rowPart = (float4*)p;  p += (size_t)n * FNS * 16;
        float4* colPart = (float4*)p;  p += (size_t)n * (NXT * 2) * 16;
        float4* tAB = (float4*)p;      p += (size_t)n * 16;
        float4* tBA = (float4*)p;

        dim3 n2grid((2 * n + 255) / 256);
        norms2_kernel<<<n2grid, blk, 0, stream>>>(A, B, invA, invB, n);
        dim3 s2grid((2 * n * 32 + 255) / 256);
        split2_kernel<<<s2grid, blk, 0, stream>>>(A, B, Ah, Al6, Bh, Bl6, n);

        dim3 grid(n / 256, FNS);
        dim3 blk1024(1024);
        mfma_top2_16w<<<grid, blk1024, 0, stream>>>(Ah, Al6, Bh, Bl6, invA, invB,
                                                    rowPart, colPart, n);

        merge2_kernel<<<n2grid, blk, 0, stream>>>(rowPart, FNS, colPart, NXT * 2,
                                                  tAB, tBA, n);
        match_kernel<<<ngrid, blk, 0, stream>>>(tAB, tBA, (float*)d_out, n);
    } else {
        // fallback: round-2 verified fused fp32 path
        float* ws = (float*)d_ws;
        float* invA = ws;
        float* invB = ws + n;
        float4* rowPart = (float4*)(ws + 2 * (size_t)n);
        float4* colPart = rowPart + (size_t)n * FNS;
        float4* tAB     = colPart + (size_t)n * (n / FBM);
        float4* tBA     = tAB + n;

        norms_kernel<<<ngrid, blk, 0, stream>>>(A, invA, n);
        norms_kernel<<<ngrid, blk, 0, stream>>>(B, invB, n);
        dim3 grid(n / FBM, FNS);
        gemm_both_top2<<<grid, blk, 0, stream>>>(A, B, invA, invB, rowPart, colPart, n);
        merge_part<<<ngrid, blk, 0, stream>>>(rowPart, tAB, n, FNS);
        merge_part<<<ngrid, blk, 0, stream>>>(colPart, tBA, n, n / FBM);
        match_kernel<<<ngrid, blk, 0, stream>>>(tAB, tBA, (float*)d_out, n);
    }
}